// Round 1
// baseline (246.671 us; speedup 1.0000x reference)
//
#include <hip/hip_runtime.h>

#define HH 512
#define WW 512
#define NPART 11
#define NP 10            // parts actually used (drop last)
#define NB 16
#define NBP (NB * NP)    // 160 channels
#define CHUNKS 16
#define ROWS_PER_CHUNK (HH / CHUNKS)           // 32
#define BLOCK 256
#define F4_PER_CHUNK (ROWS_PER_CHUNK * WW / 4) // 4096 float4 per chunk
#define ITERS (F4_PER_CHUNK / (BLOCK * 2))     // 8 iterations, 2 float4 each

// Stage 1: per (channel, chunk) block computes 5 weighted partial sums.
// ws layout: ws[(bp*CHUNKS + chunk)*5 + {S,Sx,Sy,Sx2,Sy2}]
__global__ __launch_bounds__(BLOCK) void partial_kernel(
    const float* __restrict__ in, float* __restrict__ ws) {
  const int blk = blockIdx.x;             // 0..2559
  const int bp = blk / CHUNKS;            // 0..159
  const int chunk = blk - bp * CHUNKS;    // 0..15
  const int b = bp / NP;
  const int p = bp - b * NP;

  const float4* __restrict__ in4 =
      (const float4*)(in + ((size_t)(b * NPART + p) * HH +
                            (size_t)chunk * ROWS_PER_CHUNK) * WW);
  const int t = threadIdx.x;
  const float inv256 = 1.0f / 256.0f;  // 2/W = 2/H = 1/256

  // Column map is loop-invariant per thread: fi & 127 == t & 127
  const int w0 = (t & 127) << 2;
  const float xm0 = (float)w0 * inv256 - 1.0f;
  const float xm1 = xm0 + inv256;
  const float xm2 = xm0 + 2.0f * inv256;
  const float xm3 = xm0 + 3.0f * inv256;
  const float xq0 = xm0 * xm0, xq1 = xm1 * xm1, xq2 = xm2 * xm2, xq3 = xm3 * xm3;

  // y map advances exactly 4 rows per iteration: ym(j) = base + j*(1/64).
  // All values are multiples of 2^-8 -> exact in fp32, no drift.
  float ymA = (float)(chunk * ROWS_PER_CHUNK + (t >> 7)) * inv256 - 1.0f;
  const float ym_step = 4.0f * inv256;   // 1/64, rows advance by 4 per iter
  const float ym_delta = 2.0f * inv256;  // second float4 slot is 2 rows below

  // Two independent accumulator sets (one per float4 stream) halve every
  // FMA dependency chain; merged after the loop.
  float s0 = 0.f, sx0 = 0.f, sy0 = 0.f, sx20 = 0.f, sy20 = 0.f;
  float s1 = 0.f, sx1 = 0.f, sy1 = 0.f, sx21 = 0.f, sy21 = 0.f;

  #pragma unroll
  for (int j = 0; j < ITERS; ++j) {
    const int fi0 = (j * 2) * BLOCK + t;       // two float4 slots per iter
    const float4 v0 = in4[fi0];
    const float4 v1 = in4[fi0 + BLOCK];

    const float ym0 = ymA;
    const float ym1 = ymA + ym_delta;
    ymA += ym_step;

    const float sum0 = (v0.x + v0.y) + (v0.z + v0.w);
    const float sum1 = (v1.x + v1.y) + (v1.z + v1.w);
    s0 += sum0;
    s1 += sum1;
    sy0 = fmaf(ym0, sum0, sy0);
    sy1 = fmaf(ym1, sum1, sy1);
    sy20 = fmaf(ym0 * ym0, sum0, sy20);
    sy21 = fmaf(ym1 * ym1, sum1, sy21);

    sx0 = fmaf(v0.x, xm0, sx0);  sx0 = fmaf(v0.y, xm1, sx0);
    sx0 = fmaf(v0.z, xm2, sx0);  sx0 = fmaf(v0.w, xm3, sx0);
    sx1 = fmaf(v1.x, xm0, sx1);  sx1 = fmaf(v1.y, xm1, sx1);
    sx1 = fmaf(v1.z, xm2, sx1);  sx1 = fmaf(v1.w, xm3, sx1);

    sx20 = fmaf(v0.x, xq0, sx20);  sx20 = fmaf(v0.y, xq1, sx20);
    sx20 = fmaf(v0.z, xq2, sx20);  sx20 = fmaf(v0.w, xq3, sx20);
    sx21 = fmaf(v1.x, xq0, sx21);  sx21 = fmaf(v1.y, xq1, sx21);
    sx21 = fmaf(v1.z, xq2, sx21);  sx21 = fmaf(v1.w, xq3, sx21);
  }

  float s = s0 + s1;
  float sx = sx0 + sx1;
  float sy = sy0 + sy1;
  float sx2 = sx20 + sx21;
  float sy2 = sy20 + sy21;

  // wave (64-lane) butterfly reduce for all 5 accumulators
  #pragma unroll
  for (int off = 32; off > 0; off >>= 1) {
    s   += __shfl_xor(s, off);
    sx  += __shfl_xor(sx, off);
    sy  += __shfl_xor(sy, off);
    sx2 += __shfl_xor(sx2, off);
    sy2 += __shfl_xor(sy2, off);
  }

  __shared__ float red[BLOCK / 64][5];
  const int wave = t >> 6;
  const int lane = t & 63;
  if (lane == 0) {
    red[wave][0] = s;
    red[wave][1] = sx;
    red[wave][2] = sy;
    red[wave][3] = sx2;
    red[wave][4] = sy2;
  }
  __syncthreads();
  if (t < 5) {
    float acc = red[0][t] + red[1][t] + red[2][t] + red[3][t];
    ws[(size_t)blk * 5 + t] = acc;
  }
}

// Stage 2: fold chunk partials per channel, apply centroid-variance algebra,
// reduce 160 contributions, write loss / B.
__global__ __launch_bounds__(BLOCK) void finalize_kernel(
    const float* __restrict__ ws, float* __restrict__ out) {
  const int t = threadIdx.x;
  float c = 0.f;
  if (t < NBP) {
    float S = 0.f, Sx = 0.f, Sy = 0.f, Sx2 = 0.f, Sy2 = 0.f;
    #pragma unroll
    for (int ch = 0; ch < CHUNKS; ++ch) {
      const float* q = ws + (size_t)(t * CHUNKS + ch) * 5;
      S   += q[0];
      Sx  += q[1];
      Sy  += q[2];
      Sx2 += q[3];
      Sy2 += q[4];
    }
    const float k = S + 1e-8f;
    const float inv = 1.0f / k;
    const float xc = Sx * inv;
    const float yc = Sy * inv;
    const float vx = (Sx2 - 2.0f * xc * Sx + xc * xc * S) * inv;
    const float vy = (Sy2 - 2.0f * yc * Sy + yc * yc * S) * inv;
    c = vx + vy;
  }

  #pragma unroll
  for (int off = 32; off > 0; off >>= 1) {
    c += __shfl_xor(c, off);
  }

  __shared__ float red[BLOCK / 64];
  const int wave = t >> 6;
  const int lane = t & 63;
  if (lane == 0) red[wave] = c;
  __syncthreads();
  if (t == 0) {
    float total = red[0] + red[1] + red[2] + red[3];
    out[0] = total * (1.0f / (float)NB);
  }
}

extern "C" void kernel_launch(void* const* d_in, const int* in_sizes, int n_in,
                              void* d_out, int out_size, void* d_ws, size_t ws_size,
                              hipStream_t stream) {
  const float* in = (const float*)d_in[0];
  float* out = (float*)d_out;
  float* ws = (float*)d_ws;  // needs NBP*CHUNKS*5*4 = 51,200 B

  partial_kernel<<<NBP * CHUNKS, BLOCK, 0, stream>>>(in, ws);
  finalize_kernel<<<1, BLOCK, 0, stream>>>(ws, out);
}